// Round 9
// baseline (90.060 us; speedup 1.0000x reference)
//
#include <hip/hip_runtime.h>
#include <math.h>

#define BB 8
#define TT 128
#define U1 65
#define UU 64
#define VV 1024
#define CSTR 130            // comb row stride (pairs)
#define COMB_N 8456         // 65*130 pairs + pad; max prefetch idx 8455 — exact fit
#define NEGINF -1e30f
#define LOG2E 1.4426950408889634f
#define LN2   0.6931471805599453f

// shfl_up by 1 via DPP wave_shr:1 (HW-verified rounds 2-8)
__device__ __forceinline__ float shfl_up1(float x) {
  return __int_as_float(__builtin_amdgcn_update_dpp(
      0, __float_as_int(x), 0x138, 0xf, 0xf, false));
}

// log-add-exp in log2 domain: native v_exp_f32 / v_log_f32
__device__ __forceinline__ float lae2(float a, float b) {
  const float mx = fmaxf(a, b);
  const float nd = fminf(a - b, b - a);     // -|a-b|
  return mx + log2f(1.f + exp2f(nd));
}

// ---------------- Kernel 1: logsumexp + fused comb emit (round-3 frozen) -----
__global__ __launch_bounds__(256) void lse_gather(
    const float* __restrict__ logits, const int* __restrict__ y,
    const int* __restrict__ logit_lens, const int* __restrict__ y_lens,
    float* __restrict__ comb) {
  const int wave = threadIdx.x >> 6;
  const int lane = threadIdx.x & 63;
  const int row  = blockIdx.x * 4 + wave;          // row in [0, B*T*U1)
  const int u  = row % U1;
  const int bt = row / U1;
  const int b  = bt / TT;
  const int t  = bt % TT;

  float* cb = comb + (size_t)b * COMB_N * 2;

  if (lane == 0) {
    if (t == 0) cb[2 * (u * CSTR) + 0] = NEGINF;           // comb[u][0].x
    if (u == 0) cb[2 * t + 1]          = NEGINF;           // comb[0][t].y
  }
  if (t >= logit_lens[b] || u > y_lens[b]) return;         // row not on result path

  const float4* rp = (const float4*)(logits + (size_t)row * VV);
  float4 x0 = rp[lane];
  float4 x1 = rp[lane + 64];
  float4 x2 = rp[lane + 128];
  float4 x3 = rp[lane + 192];

  const bool have_label = (u < UU);
  float lab_logit = 0.f;
  if (have_label && lane == 0)
    lab_logit = logits[(size_t)row * VV + y[b * UU + u]];  // L1/L2 hit

  float m = fmaxf(fmaxf(fmaxf(x0.x, x0.y), fmaxf(x0.z, x0.w)),
                  fmaxf(fmaxf(x1.x, x1.y), fmaxf(x1.z, x1.w)));
  m = fmaxf(m, fmaxf(fmaxf(fmaxf(x2.x, x2.y), fmaxf(x2.z, x2.w)),
                     fmaxf(fmaxf(x3.x, x3.y), fmaxf(x3.z, x3.w))));
#pragma unroll
  for (int s = 32; s >= 1; s >>= 1) m = fmaxf(m, __shfl_xor(m, s));

  float ss = __expf(x0.x - m) + __expf(x0.y - m) + __expf(x0.z - m) + __expf(x0.w - m)
           + __expf(x1.x - m) + __expf(x1.y - m) + __expf(x1.z - m) + __expf(x1.w - m)
           + __expf(x2.x - m) + __expf(x2.y - m) + __expf(x2.z - m) + __expf(x2.w - m)
           + __expf(x3.x - m) + __expf(x3.y - m) + __expf(x3.z - m) + __expf(x3.w - m);
#pragma unroll
  for (int s = 32; s >= 1; s >>= 1) ss += __shfl_xor(ss, s);

  if (lane == 0) {
    const float lse = m + __logf(ss);
    cb[2 * (u * CSTR + t + 1) + 0] = (x0.x - lse) * LOG2E;          // blank
    if (have_label)
      cb[2 * ((u + 1) * CSTR + t) + 1] = (lab_logit - lse) * LOG2E; // label
  }
}

// ---------------- Kernel 2: alpha DP straight from GLOBAL (no LDS) -----------
// 1 wave/block. Per-lane stream cp[d] walks 8B/iter: 64-line (4KB) working set
// stays L1-resident; 8-deep named-register prefetch hides L1/L2 latency.
__global__ __launch_bounds__(64) void alpha_dp_g(
    const float2* __restrict__ comb, const int* __restrict__ logit_lens,
    const int* __restrict__ y_lens, float* __restrict__ losses) {
  const int b = blockIdx.x;
  const int lane = threadIdx.x;

  const int tEnd = logit_lens[b] - 1;   // in [63,127]
  const int uEnd = y_lens[b];           // in [32,64]
  const int dT   = tEnd + uEnd;         // in [95,191]

  const float2* cg   = comb + (size_t)b * COMB_N;
  const float2* cp   = cg + 129 * lane;   // cp[d] = comb[u][d-u]
  const float2* cp64 = cg + 8256;         // cp64[d] = comb[64][d-64] (broadcast)

  float A   = (lane == 0) ? 0.f : NEGINF;
  float A64 = NEGINF;

#define STEP(cc, ee)                                      \
  {                                                       \
    const float aleft = shfl_up1(A);                      \
    const float top   = A + (cc).x;                       \
    const float lft   = aleft + (cc).y;                   \
    const float xt    = A64 + (ee).x;                     \
    const float xl    = A + (ee).y;   /* pre-update A */  \
    A   = lae2(top, lft);                                 \
    A64 = lae2(xt, xl);                                   \
  }

  // preload d = 1..8
  float2 c0 = cp[1], c1 = cp[2], c2 = cp[3], c3 = cp[4],
         c4 = cp[5], c5 = cp[6], c6 = cp[7], c7 = cp[8];
  float2 e0 = cp64[1], e1 = cp64[2], e2 = cp64[3], e3 = cp64[4],
         e4 = cp64[5], e5 = cp64[6], e6 = cp64[7], e7 = cp64[8];

  int d = 1;
  for (; d + 7 <= dT; d += 8) {
    const float2 n0 = cp[d + 8],  n1 = cp[d + 9],  n2 = cp[d + 10], n3 = cp[d + 11];
    const float2 n4 = cp[d + 12], n5 = cp[d + 13], n6 = cp[d + 14], n7 = cp[d + 15];
    const float2 f0 = cp64[d + 8],  f1 = cp64[d + 9],  f2 = cp64[d + 10], f3 = cp64[d + 11];
    const float2 f4 = cp64[d + 12], f5 = cp64[d + 13], f6 = cp64[d + 14], f7 = cp64[d + 15];
    STEP(c0, e0) STEP(c1, e1) STEP(c2, e2) STEP(c3, e3)
    STEP(c4, e4) STEP(c5, e5) STEP(c6, e6) STEP(c7, e7)
    c0 = n0; c1 = n1; c2 = n2; c3 = n3; c4 = n4; c5 = n5; c6 = n6; c7 = n7;
    e0 = f0; e1 = f1; e2 = f2; e3 = f3; e4 = f4; e5 = f5; e6 = f6; e7 = f7;
  }
  for (; d <= dT; ++d) {                 // <=7 tail iters, L1-hot direct reads
    const float2 c = cp[d], e = cp64[d];
    STEP(c, e)
  }
#undef STEP

  if (uEnd == 64) {
    if (lane == 63) losses[b] = -(A64 + cg[64 * CSTR + tEnd + 1].x) * LN2;
  } else {
    if (lane == uEnd) losses[b] = -(A + cg[uEnd * CSTR + tEnd + 1].x) * LN2;
  }
}

// ---------------- Kernel 3: mean over batch ----------------------------------
__global__ void finalize(const float* __restrict__ losses, float* __restrict__ out) {
  if (threadIdx.x == 0) {
    float s = 0.f;
#pragma unroll
    for (int i = 0; i < BB; ++i) s += losses[i];
    out[0] = s / (float)BB;
  }
}

extern "C" void kernel_launch(void* const* d_in, const int* in_sizes, int n_in,
                              void* d_out, int out_size, void* d_ws, size_t ws_size,
                              hipStream_t stream) {
  const float* logits     = (const float*)d_in[0];
  const int*   logit_lens = (const int*)d_in[1];
  const int*   y          = (const int*)d_in[2];
  const int*   y_lens     = (const int*)d_in[3];
  float* out = (float*)d_out;

  float2* comb   = (float2*)d_ws;                       // BB * COMB_N pairs
  float*  losses = (float*)(comb + (size_t)BB * COMB_N);

  const int rows = BB * TT * U1;                        // 66560
  lse_gather<<<rows / 4, 256, 0, stream>>>(logits, y, logit_lens, y_lens, (float*)comb);
  // alpha x3: byte-identical writes — marginal-cost probe rides along with the
  // staging-removal experiment. Round 10 drops to a single launch.
  alpha_dp_g<<<BB, 64, 0, stream>>>(comb, logit_lens, y_lens, losses);
  alpha_dp_g<<<BB, 64, 0, stream>>>(comb, logit_lens, y_lens, losses);
  alpha_dp_g<<<BB, 64, 0, stream>>>(comb, logit_lens, y_lens, losses);
  finalize<<<1, 64, 0, stream>>>(losses, out);
}

// Round 10
// 62.852 us; speedup vs baseline: 1.4329x; 1.4329x over previous
//
#include <hip/hip_runtime.h>
#include <math.h>

#define BB 8
#define TT 128
#define U1 65
#define UU 64
#define VV 1024
#define DSTR 66             // pairs per diagonal row (65 used + 1 pad; 528B, 16-aligned)
#define NDIAG 200           // diagonals 0..192 used; prefetch overruns to 199
#define NEGINF -1e30f
#define LOG2E 1.4426950408889634f
#define LN2   0.6931471805599453f

// shfl_up by 1 via DPP wave_shr:1 (HW-verified rounds 2-9; lane 0 receives 0)
__device__ __forceinline__ float shfl_up1(float x) {
  return __int_as_float(__builtin_amdgcn_update_dpp(
      0, __float_as_int(x), 0x138, 0xf, 0xf, false));
}

// log-add-exp in log2 domain: native v_exp_f32 / v_log_f32
__device__ __forceinline__ float lae2(float a, float b) {
  const float mx = fmaxf(a, b);
  const float nd = fminf(a - b, b - a);     // -|a-b|
  return mx + log2f(1.f + exp2f(nd));
}

// ---------------- Kernel 1: logsumexp + DIAGONAL-major comb emit -------------
// cd[b][d][u] = ( blank'[d-u-1][u], label'[d-u][u-1] )  (log2 scale)
// Row (t,u) writes both outputs at diagonal d=t+u+1 (lanes u, u+1).
// Padding: t=0 row -> cd[u][u].x=-inf ; u=0 row -> cd[t+1][0].y=-inf.
__global__ __launch_bounds__(256) void lse_gather(
    const float* __restrict__ logits, const int* __restrict__ y,
    const int* __restrict__ logit_lens, const int* __restrict__ y_lens,
    float* __restrict__ comb) {
  const int wave = threadIdx.x >> 6;
  const int lane = threadIdx.x & 63;
  const int row  = blockIdx.x * 4 + wave;          // row in [0, B*T*U1)
  const int u  = row % U1;
  const int bt = row / U1;
  const int b  = bt / TT;
  const int t  = bt % TT;

  float* cb = comb + (size_t)b * NDIAG * DSTR * 2;

  // structural padding — writers are never-skipped rows (t=0 / u=0 always valid)
  if (lane == 0) {
    if (t == 0) cb[2 * (u * DSTR + u) + 0]   = NEGINF;   // cd[u][u].x  (t=0: no top)
    if (u == 0) cb[2 * ((t + 1) * DSTR) + 1] = NEGINF;   // cd[t+1][0].y (u=0: no left)
  }
  if (t >= logit_lens[b] || u > y_lens[b]) return;       // row not on result path

  const float4* rp = (const float4*)(logits + (size_t)row * VV);
  float4 x0 = rp[lane];
  float4 x1 = rp[lane + 64];
  float4 x2 = rp[lane + 128];
  float4 x3 = rp[lane + 192];

  const bool have_label = (u < UU);
  float lab_logit = 0.f;
  if (have_label && lane == 0)
    lab_logit = logits[(size_t)row * VV + y[b * UU + u]];  // L1/L2 hit

  float m = fmaxf(fmaxf(fmaxf(x0.x, x0.y), fmaxf(x0.z, x0.w)),
                  fmaxf(fmaxf(x1.x, x1.y), fmaxf(x1.z, x1.w)));
  m = fmaxf(m, fmaxf(fmaxf(fmaxf(x2.x, x2.y), fmaxf(x2.z, x2.w)),
                     fmaxf(fmaxf(x3.x, x3.y), fmaxf(x3.z, x3.w))));
#pragma unroll
  for (int s = 32; s >= 1; s >>= 1) m = fmaxf(m, __shfl_xor(m, s));

  float ss = __expf(x0.x - m) + __expf(x0.y - m) + __expf(x0.z - m) + __expf(x0.w - m)
           + __expf(x1.x - m) + __expf(x1.y - m) + __expf(x1.z - m) + __expf(x1.w - m)
           + __expf(x2.x - m) + __expf(x2.y - m) + __expf(x2.z - m) + __expf(x2.w - m)
           + __expf(x3.x - m) + __expf(x3.y - m) + __expf(x3.z - m) + __expf(x3.w - m);
#pragma unroll
  for (int s = 32; s >= 1; s >>= 1) ss += __shfl_xor(ss, s);

  if (lane == 0) {
    const float lse = m + __logf(ss);
    const int dd = t + u + 1;
    cb[2 * (dd * DSTR + u) + 0] = (x0.x - lse) * LOG2E;            // blank'[t][u]
    if (have_label)
      cb[2 * (dd * DSTR + u + 1) + 1] = (lab_logit - lse) * LOG2E; // label'[t][u]
  }
}

// ---------------- Kernel 2: alpha DP, 1 block x 8 waves, fused mean ----------
// Wave w = batch b. Per iteration: ONE coalesced 520B wave-load cd[d][0..64]
// (9 cache lines vs 128 in round 9) + broadcast e-pair. 8-deep named prefetch.
__global__ __launch_bounds__(512) void alpha_all(
    const float2* __restrict__ comb, const int* __restrict__ logit_lens,
    const int* __restrict__ y_lens, float* __restrict__ out) {
  const int w    = threadIdx.x >> 6;    // wave = batch
  const int lane = threadIdx.x & 63;
  const int b    = w;
  __shared__ float sl[BB];

  const int tEnd = logit_lens[b] - 1;   // in [63,127]
  const int uEnd = y_lens[b];           // in [32,64]
  const int dT   = tEnd + uEnd;         // in [95,191]

  const float2* cg = comb + (size_t)b * NDIAG * DSTR;
  const float2* cp = cg + lane;         // cp[66*d] = cd[d][lane]   (coalesced)
  const float2* ce = cg + 64;           // ce[66*d] = cd[d][64]     (broadcast)

  float A   = (lane == 0) ? 0.f : NEGINF;
  float A64 = NEGINF;

#define STEP(cc, ee)                                      \
  {                                                       \
    const float aleft = shfl_up1(A);                      \
    const float top   = A + (cc).x;                       \
    const float lft   = aleft + (cc).y;                   \
    const float xt    = A64 + (ee).x;                     \
    const float xl    = A + (ee).y;   /* pre-update A */  \
    A   = lae2(top, lft);                                 \
    A64 = lae2(xt, xl);                                   \
  }

  // preload d = 1..8
  float2 c0 = cp[66 * 1], c1 = cp[66 * 2], c2 = cp[66 * 3], c3 = cp[66 * 4],
         c4 = cp[66 * 5], c5 = cp[66 * 6], c6 = cp[66 * 7], c7 = cp[66 * 8];
  float2 e0 = ce[66 * 1], e1 = ce[66 * 2], e2 = ce[66 * 3], e3 = ce[66 * 4],
         e4 = ce[66 * 5], e5 = ce[66 * 6], e6 = ce[66 * 7], e7 = ce[66 * 8];

  int d = 1;
  for (; d + 7 <= dT; d += 8) {
    const float2 n0 = cp[66 * (d + 8)],  n1 = cp[66 * (d + 9)];
    const float2 n2 = cp[66 * (d + 10)], n3 = cp[66 * (d + 11)];
    const float2 n4 = cp[66 * (d + 12)], n5 = cp[66 * (d + 13)];
    const float2 n6 = cp[66 * (d + 14)], n7 = cp[66 * (d + 15)];
    const float2 f0 = ce[66 * (d + 8)],  f1 = ce[66 * (d + 9)];
    const float2 f2 = ce[66 * (d + 10)], f3 = ce[66 * (d + 11)];
    const float2 f4 = ce[66 * (d + 12)], f5 = ce[66 * (d + 13)];
    const float2 f6 = ce[66 * (d + 14)], f7 = ce[66 * (d + 15)];
    STEP(c0, e0) STEP(c1, e1) STEP(c2, e2) STEP(c3, e3)
    STEP(c4, e4) STEP(c5, e5) STEP(c6, e6) STEP(c7, e7)
    c0 = n0; c1 = n1; c2 = n2; c3 = n3; c4 = n4; c5 = n5; c6 = n6; c7 = n7;
    e0 = f0; e1 = f1; e2 = f2; e3 = f3; e4 = f4; e5 = f5; e6 = f6; e7 = f7;
  }
  // tail: consume already-loaded registers (<=7 steps, wave-uniform guards)
  if (d <= dT) { STEP(c0, e0) ++d; }
  if (d <= dT) { STEP(c1, e1) ++d; }
  if (d <= dT) { STEP(c2, e2) ++d; }
  if (d <= dT) { STEP(c3, e3) ++d; }
  if (d <= dT) { STEP(c4, e4) ++d; }
  if (d <= dT) { STEP(c5, e5) ++d; }
  if (d <= dT) { STEP(c6, e6) ++d; }
#undef STEP

  // loss_b = -(alpha'[tEnd][uEnd] + blank'[tEnd][uEnd]) * ln2
  const float R   = (uEnd == 64) ? A64 : A;
  const int   sel = (uEnd == 64) ? 63 : uEnd;
  if (lane == sel)
    sl[b] = -(R + cg[(dT + 1) * DSTR + uEnd].x) * LN2;

  __syncthreads();
  if (threadIdx.x == 0) {
    float s = 0.f;
#pragma unroll
    for (int i = 0; i < BB; ++i) s += sl[i];
    out[0] = s * (1.f / BB);
  }
}

extern "C" void kernel_launch(void* const* d_in, const int* in_sizes, int n_in,
                              void* d_out, int out_size, void* d_ws, size_t ws_size,
                              hipStream_t stream) {
  const float* logits     = (const float*)d_in[0];
  const int*   logit_lens = (const int*)d_in[1];
  const int*   y          = (const int*)d_in[2];
  const int*   y_lens     = (const int*)d_in[3];
  float* out = (float*)d_out;

  float2* comb = (float2*)d_ws;                 // BB * NDIAG * DSTR pairs (~845 KB)

  const int rows = BB * TT * U1;                // 66560
  lse_gather<<<rows / 4, 256, 0, stream>>>(logits, y, logit_lens, y_lens, (float*)comb);
  alpha_all<<<1, 512, 0, stream>>>(comb, logit_lens, y_lens, out);
}

// Round 11
// 50.667 us; speedup vs baseline: 1.7775x; 1.2405x over previous
//
#include <hip/hip_runtime.h>
#include <math.h>

#define BB 8
#define TT 128
#define U1 65
#define UU 64
#define VV 1024
#define DSTR 66             // pairs per diagonal row (65 used + 1 pad)
#define NDIAG 208           // diagonals 0..192 used; prefetch overruns to 206
#define NEGINF -1e30f
#define LOG2E 1.4426950408889634f
#define LN2   0.6931471805599453f

// shfl_up by 1 via DPP wave_shr:1 (HW-verified rounds 2-10; lane 0 receives 0)
__device__ __forceinline__ float shfl_up1(float x) {
  return __int_as_float(__builtin_amdgcn_update_dpp(
      0, __float_as_int(x), 0x138, 0xf, 0xf, false));
}

// log-add-exp in log2 domain on RAW HW ops: v_exp_f32 (with -|x| input
// modifier) + v_log_f32. No ocml calls on the serial DP chain.
__device__ __forceinline__ float lae2(float a, float b) {
  const float e = __builtin_amdgcn_exp2f(-fabsf(a - b));
  return fmaxf(a, b) + __builtin_amdgcn_logf(1.f + e);
}

// ---------------- Kernel 1: logsumexp + DIAGONAL-major comb emit -------------
// cd[b][d][u] = ( blank'[d-u-1][u], label'[d-u][u-1] )  (log2 scale)
// Row (t,u) writes both outputs at diagonal d=t+u+1 (slots u, u+1).
// Padding: t=0 row -> cd[u][u].x=-inf ; u=0 row -> cd[t+1][0].y=-inf.
__global__ __launch_bounds__(256) void lse_gather(
    const float* __restrict__ logits, const int* __restrict__ y,
    const int* __restrict__ logit_lens, const int* __restrict__ y_lens,
    float* __restrict__ comb) {
  const int wave = threadIdx.x >> 6;
  const int lane = threadIdx.x & 63;
  const int row  = blockIdx.x * 4 + wave;          // row in [0, B*T*U1)
  const int u  = row % U1;
  const int bt = row / U1;
  const int b  = bt / TT;
  const int t  = bt % TT;

  float* cb = comb + (size_t)b * NDIAG * DSTR * 2;

  // structural padding — writers are never-skipped rows (t=0 / u=0 always valid)
  if (lane == 0) {
    if (t == 0) cb[2 * (u * DSTR + u) + 0]   = NEGINF;   // cd[u][u].x  (t=0: no top)
    if (u == 0) cb[2 * ((t + 1) * DSTR) + 1] = NEGINF;   // cd[t+1][0].y (u=0: no left)
  }
  if (t >= logit_lens[b] || u > y_lens[b]) return;       // row not on result path

  const float4* rp = (const float4*)(logits + (size_t)row * VV);
  float4 x0 = rp[lane];
  float4 x1 = rp[lane + 64];
  float4 x2 = rp[lane + 128];
  float4 x3 = rp[lane + 192];

  const bool have_label = (u < UU);
  float lab_logit = 0.f;
  if (have_label && lane == 0)
    lab_logit = logits[(size_t)row * VV + y[b * UU + u]];  // L1/L2 hit

  float m = fmaxf(fmaxf(fmaxf(x0.x, x0.y), fmaxf(x0.z, x0.w)),
                  fmaxf(fmaxf(x1.x, x1.y), fmaxf(x1.z, x1.w)));
  m = fmaxf(m, fmaxf(fmaxf(fmaxf(x2.x, x2.y), fmaxf(x2.z, x2.w)),
                     fmaxf(fmaxf(x3.x, x3.y), fmaxf(x3.z, x3.w))));
#pragma unroll
  for (int s = 32; s >= 1; s >>= 1) m = fmaxf(m, __shfl_xor(m, s));

  float ss = __expf(x0.x - m) + __expf(x0.y - m) + __expf(x0.z - m) + __expf(x0.w - m)
           + __expf(x1.x - m) + __expf(x1.y - m) + __expf(x1.z - m) + __expf(x1.w - m)
           + __expf(x2.x - m) + __expf(x2.y - m) + __expf(x2.z - m) + __expf(x2.w - m)
           + __expf(x3.x - m) + __expf(x3.y - m) + __expf(x3.z - m) + __expf(x3.w - m);
#pragma unroll
  for (int s = 32; s >= 1; s >>= 1) ss += __shfl_xor(ss, s);

  if (lane == 0) {
    const float lse = m + __logf(ss);
    const int dd = t + u + 1;
    cb[2 * (dd * DSTR + u) + 0] = (x0.x - lse) * LOG2E;            // blank'[t][u]
    if (have_label)
      cb[2 * (dd * DSTR + u + 1) + 1] = (lab_logit - lse) * LOG2E; // label'[t][u]
  }
}

// ---------------- Kernel 2: alpha DP, 8 blocks x 1 wave, native-op chain -----
// Per iteration: one coalesced 520B wave-load cd[d][0..64] + uniform e-pair.
// 8-deep named prefetch; serial chain is ~7 native VALU ops per step.
__global__ __launch_bounds__(64) void alpha_dp(
    const float2* __restrict__ comb, const int* __restrict__ logit_lens,
    const int* __restrict__ y_lens, float* __restrict__ losses) {
  const int b    = blockIdx.x;
  const int lane = threadIdx.x;

  const int tEnd = logit_lens[b] - 1;   // in [63,127]
  const int uEnd = y_lens[b];           // in [32,64]
  const int dT   = tEnd + uEnd;         // in [95,191]

  const float2* cg = comb + (size_t)b * NDIAG * DSTR;
  const float2* cp = cg + lane;         // cp[66*d] = cd[d][lane]   (coalesced)
  const float2* ce = cg + 64;           // ce[66*d] = cd[d][64]     (uniform)

  float A   = (lane == 0) ? 0.f : NEGINF;
  float A64 = NEGINF;

#define STEP(cc, ee)                                      \
  {                                                       \
    const float aleft = shfl_up1(A);                      \
    const float top   = A + (cc).x;                       \
    const float lft   = aleft + (cc).y;                   \
    const float xt    = A64 + (ee).x;                     \
    const float xl    = A + (ee).y;   /* pre-update A */  \
    A   = lae2(top, lft);                                 \
    A64 = lae2(xt, xl);                                   \
  }

  // preload d = 1..8
  float2 c0 = cp[66 * 1], c1 = cp[66 * 2], c2 = cp[66 * 3], c3 = cp[66 * 4],
         c4 = cp[66 * 5], c5 = cp[66 * 6], c6 = cp[66 * 7], c7 = cp[66 * 8];
  float2 e0 = ce[66 * 1], e1 = ce[66 * 2], e2 = ce[66 * 3], e3 = ce[66 * 4],
         e4 = ce[66 * 5], e5 = ce[66 * 6], e6 = ce[66 * 7], e7 = ce[66 * 8];

  int d = 1;
  for (; d + 7 <= dT; d += 8) {
    const float2 n0 = cp[66 * (d + 8)],  n1 = cp[66 * (d + 9)];
    const float2 n2 = cp[66 * (d + 10)], n3 = cp[66 * (d + 11)];
    const float2 n4 = cp[66 * (d + 12)], n5 = cp[66 * (d + 13)];
    const float2 n6 = cp[66 * (d + 14)], n7 = cp[66 * (d + 15)];
    const float2 f0 = ce[66 * (d + 8)],  f1 = ce[66 * (d + 9)];
    const float2 f2 = ce[66 * (d + 10)], f3 = ce[66 * (d + 11)];
    const float2 f4 = ce[66 * (d + 12)], f5 = ce[66 * (d + 13)];
    const float2 f6 = ce[66 * (d + 14)], f7 = ce[66 * (d + 15)];
    STEP(c0, e0) STEP(c1, e1) STEP(c2, e2) STEP(c3, e3)
    STEP(c4, e4) STEP(c5, e5) STEP(c6, e6) STEP(c7, e7)
    c0 = n0; c1 = n1; c2 = n2; c3 = n3; c4 = n4; c5 = n5; c6 = n6; c7 = n7;
    e0 = f0; e1 = f1; e2 = f2; e3 = f3; e4 = f4; e5 = f5; e6 = f6; e7 = f7;
  }
  // tail: consume already-loaded registers (<=7 steps, wave-uniform guards)
  if (d <= dT) { STEP(c0, e0) ++d; }
  if (d <= dT) { STEP(c1, e1) ++d; }
  if (d <= dT) { STEP(c2, e2) ++d; }
  if (d <= dT) { STEP(c3, e3) ++d; }
  if (d <= dT) { STEP(c4, e4) ++d; }
  if (d <= dT) { STEP(c5, e5) ++d; }
  if (d <= dT) { STEP(c6, e6) ++d; }
#undef STEP

  // loss_b = -(alpha'[tEnd][uEnd] + blank'[tEnd][uEnd]) * ln2
  const float R   = (uEnd == 64) ? A64 : A;
  const int   sel = (uEnd == 64) ? 63 : uEnd;
  if (lane == sel)
    losses[b] = -(R + cg[(dT + 1) * DSTR + uEnd].x) * LN2;
}

// ---------------- Kernel 3: mean over batch ----------------------------------
__global__ void finalize(const float* __restrict__ losses, float* __restrict__ out) {
  if (threadIdx.x == 0) {
    float s = 0.f;
#pragma unroll
    for (int i = 0; i < BB; ++i) s += losses[i];
    out[0] = s / (float)BB;
  }
}

extern "C" void kernel_launch(void* const* d_in, const int* in_sizes, int n_in,
                              void* d_out, int out_size, void* d_ws, size_t ws_size,
                              hipStream_t stream) {
  const float* logits     = (const float*)d_in[0];
  const int*   logit_lens = (const int*)d_in[1];
  const int*   y          = (const int*)d_in[2];
  const int*   y_lens     = (const int*)d_in[3];
  float* out = (float*)d_out;

  float2* comb   = (float2*)d_ws;                 // BB * NDIAG * DSTR pairs (~878 KB)
  float*  losses = (float*)(comb + (size_t)BB * NDIAG * DSTR);

  const int rows = BB * TT * U1;                  // 66560
  lse_gather<<<rows / 4, 256, 0, stream>>>(logits, y, logit_lens, y_lens, (float*)comb);
  alpha_dp<<<BB, 64, 0, stream>>>(comb, logit_lens, y_lens, losses);
  finalize<<<1, 64, 0, stream>>>(losses, out);
}